// Round 6
// baseline (1301.485 us; speedup 1.0000x reference)
//
#include <hip/hip_runtime.h>
#include <math.h>
#include <limits.h>

#define D 1024  // state dim, fixed by the problem

typedef float f32x4 __attribute__((ext_vector_type(4)));

__device__ __forceinline__ float sigmoidf_(float v) {
    return 1.0f / (1.0f + expf(-v));
}

// Block-wide sum reduce for blockDim.x == 256 (4 waves). Broadcasts result.
// Trailing barrier makes repeated calls safe.
__device__ __forceinline__ float block_reduce_sum256(float v) {
    #pragma unroll
    for (int off = 32; off; off >>= 1) v += __shfl_down(v, off, 64);
    __shared__ float sm[4];
    int lane = threadIdx.x & 63, w = threadIdx.x >> 6;
    if (lane == 0) sm[w] = v;
    __syncthreads();
    float s = sm[0] + sm[1] + sm[2] + sm[3];
    __syncthreads();
    return s;
}

// Grid = N_T1 blocks. Every block: grid-stride init of the interleaved flag
// array to -1 (2N ints, <=1 store per thread). Then tmp[row] = T[row,:]@W_T_2.
__global__ void k_pre(const float* __restrict__ T,
                      const float* __restrict__ w,
                      float* __restrict__ tmp,
                      int* __restrict__ flags,   // int2 {tail_edge, neigh_edge}[N]
                      int n_flags, int t4 /* = N_T2/4 */) {
    const int tid = threadIdx.x;
    int gid = blockIdx.x * 256 + tid;
    int gsz = gridDim.x * 256;
    for (int i = gid; i < n_flags; i += gsz) flags[i] = -1;

    const int row = blockIdx.x;
    const float4* Tr = (const float4*)(T + (size_t)row * (size_t)(t4 * 4));
    const float4* wv = (const float4*)w;
    float acc = 0.f;
    for (int i = tid; i < t4; i += 256) {
        float4 a = Tr[i], c = wv[i];
        acc += a.x * c.x + a.y * c.y + a.z * c.z + a.w * c.w;
    }
    float s = block_reduce_sum256(acc);
    if (tid == 0) tmp[row] = s;
}

// Grid = D+1 blocks.
// Blocks [0,D): t = sigmoid(W_T_1[row,:] @ tmp + b_T[row]);
//   pu_P[row] = x[POI,row]*t ; pu_U[row] = s_u[user,row]*t.
// Block D: edge classification on the pre-initialized interleaved flags:
//   flags[2t]   (tail_edge[t])  = max e with heads[e]==POI   (np last-wins)
//   flags[2h+1] (neigh_edge[h]) = max e with e!=POI_index && tail_edge[tails[e]]>=0
__global__ void k_tvec2(const float* __restrict__ W_T_1,
                        const float* __restrict__ tmp,
                        const float* __restrict__ b_T,
                        const float* __restrict__ x,
                        const float* __restrict__ s_u,
                        const int* __restrict__ user_ptr,
                        const int* __restrict__ POI_ptr,
                        const int* __restrict__ edge_index,
                        int* __restrict__ flags,
                        float* __restrict__ pu_P,
                        float* __restrict__ pu_U,
                        int k4 /* = N_T1/4 */, int E) {
    const int tid = threadIdx.x;
    if (blockIdx.x == gridDim.x - 1) {  // classifier block
        const int POI = POI_ptr[0];
        for (int e = tid; e < E; e += 256)
            if (edge_index[e] == POI)
                atomicMax(&flags[2 * edge_index[E + e]], e);
        __syncthreads();
        for (int e = tid; e < E; e += 256) {
            if (e == POI) continue;  // neigh_mask.at[POI_index].set(False)
            // read via atomic path (L2) so phase-1 results are visible
            int te = atomicMax(&flags[2 * edge_index[E + e]], INT_MIN);
            if (te >= 0) atomicMax(&flags[2 * edge_index[e] + 1], e);
        }
        return;
    }
    const int row = blockIdx.x;  // D rows
    const float4* Wr = (const float4*)(W_T_1 + (size_t)row * (size_t)(k4 * 4));
    const float4* tv = (const float4*)tmp;
    float acc = 0.f;
    for (int i = tid; i < k4; i += 256) {
        float4 a = Wr[i], c = tv[i];
        acc += a.x * c.x + a.y * c.y + a.z * c.z + a.w * c.w;
    }
    float s = block_reduce_sum256(acc);
    if (tid == 0) {
        float t = sigmoidf_(s + b_T[row]);
        pu_P[row] = x[(size_t)POI_ptr[0] * D + row] * t;
        pu_U[row] = s_u[(size_t)user_ptr[0] * D + row] * t;
    }
}

// Grid = ceil((N_users+N)/8) blocks x 256 threads; 8 rows per block, each
// thread owns one float4 slot of all 8 rows. Hot path: flag reads (L2,
// broadcast) -> 8 bulk loads -> 8 stores, all plain accesses. The entire
// rare path sits behind one block-uniform branch.
// ALL per-row loops are #pragma unroll (trip 8) so v/te/ne/sp stay in VGPRs
// (rule #20: runtime-indexed arrays get demoted to scratch -> 5.4 GB of
// spill traffic in round 5).
// Deterministic single writer per row:
//   s_u region: user row -> sigmoid(u + W_u*dotP); else stream copy.
//   x region:   neigh winner > tail winner > POI row > stream copy,
//   neigh base = post-tail-scatter value (matches reference order).
__global__ void k_mega8(const float* __restrict__ s_u,
                        const float* __restrict__ x,
                        const float* __restrict__ edge_attr,
                        const float* __restrict__ W_u,
                        const float* __restrict__ W_p,
                        const float* __restrict__ Wp_row,
                        const int* __restrict__ user_ptr,
                        const int* __restrict__ POI_ptr,
                        const int* __restrict__ flags,  // int2 per x-row
                        const float* __restrict__ pu_P,
                        const float* __restrict__ pu_U,
                        float* __restrict__ out,
                        int N_users, int total_rows) {
    const int tid = threadIdx.x;
    const int base = blockIdx.x * 8;
    const int user = user_ptr[0], POI = POI_ptr[0];

    // 1) per-row flags first (block-uniform broadcast loads from L2)
    int te[8], ne[8];
    bool sp[8];
    bool any_sp = false;
    #pragma unroll
    for (int k = 0; k < 8; k++) {
        int r = base + k;
        te[k] = -1; ne[k] = -1; sp[k] = false;
        if (r >= total_rows) continue;
        if (r < N_users) {
            sp[k] = (r == user);
        } else {
            int j = r - N_users;
            int2 fl = ((const int2*)flags)[j];
            te[k] = fl.x; ne[k] = fl.y;
            sp[k] = ((fl.x & fl.y) != -1) || (j == POI);
        }
        any_sp |= sp[k];
    }

    // 2) bulk row loads (8 outstanding per thread)
    f32x4 v[8];
    #pragma unroll
    for (int k = 0; k < 8; k++) {
        int r = base + k;
        if (r >= total_rows) continue;
        const float* src = (r < N_users) ? s_u + (size_t)r * D
                                         : x + (size_t)(r - N_users) * D;
        v[k] = *((const f32x4*)src + tid);
    }

    // 3) hot path: pure streaming store
    if (!any_sp) {
        #pragma unroll
        for (int k = 0; k < 8; k++) {
            int r = base + k;
            if (r >= total_rows) continue;
            *((f32x4*)(out + (size_t)r * D) + tid) = v[k];
        }
        return;
    }

    // 4) rare path — MUST stay fully unrolled (constant indices -> VGPRs).
    //    Block-uniform conditions -> barrier-based reductions are safe.
    #pragma unroll
    for (int k = 0; k < 8; k++) {
        int r = base + k;
        if (r >= total_rows) continue;
        f32x4* dst = (f32x4*)(out + (size_t)r * D) + tid;
        if (!sp[k]) { *dst = v[k]; continue; }
        if (r < N_users) {  // user row
            f32x4 pp = ((const f32x4*)pu_P)[tid];
            float dotP = block_reduce_sum256(pp.x + pp.y + pp.z + pp.w);
            f32x4 wu = ((const f32x4*)W_u)[tid];
            f32x4 o;
            o.x = sigmoidf_(v[k].x + wu.x * dotP);
            o.y = sigmoidf_(v[k].y + wu.y * dotP);
            o.z = sigmoidf_(v[k].z + wu.z * dotP);
            o.w = sigmoidf_(v[k].w + wu.w * dotP);
            *dst = o;
            continue;
        }
        const int j = r - N_users;
        // new_POI element: sigmoid(x[POI] + W_p * dotU)
        f32x4 uu = ((const f32x4*)pu_U)[tid];
        float dotU = block_reduce_sum256(uu.x + uu.y + uu.z + uu.w);
        f32x4 xp = ((const f32x4*)(x + (size_t)POI * D))[tid];
        f32x4 wp = ((const f32x4*)W_p)[tid];
        f32x4 np;
        np.x = sigmoidf_(xp.x + wp.x * dotU);
        np.y = sigmoidf_(xp.y + wp.y * dotU);
        np.z = sigmoidf_(xp.z + wp.z * dotU);
        np.w = sigmoidf_(xp.w + wp.w * dotU);
        // base value: x state after POI-set and tail-scatter
        f32x4 hv;
        if (te[k] >= 0) {
            f32x4 b = ((const f32x4*)(edge_attr + (size_t)te[k] * D))[tid];
            hv = np + b;
        } else if (j == POI) {
            hv = np;
        } else {
            hv = v[k];
        }
        if (ne[k] < 0) {  // tail winner or untouched POI row
            *dst = hv;
            continue;
        }
        // neigh winner: sigmoid(hv + dot(hv - edge_attr[ne], W_p_))
        f32x4 ev = ((const f32x4*)(edge_attr + (size_t)ne[k] * D))[tid];
        f32x4 w = ((const f32x4*)Wp_row)[tid];
        f32x4 dd = hv - ev;
        float acc = dd.x * w.x + dd.y * w.y + dd.z * w.z + dd.w * w.w;
        float scal = block_reduce_sum256(acc);
        f32x4 o;
        o.x = sigmoidf_(hv.x + scal);
        o.y = sigmoidf_(hv.y + scal);
        o.z = sigmoidf_(hv.z + scal);
        o.w = sigmoidf_(hv.w + scal);
        *dst = o;
    }
}

extern "C" void kernel_launch(void* const* d_in, const int* in_sizes, int n_in,
                              void* d_out, int out_size, void* d_ws, size_t ws_size,
                              hipStream_t stream) {
    const float* s_u       = (const float*)d_in[0];
    const float* x         = (const float*)d_in[1];
    const float* edge_attr = (const float*)d_in[2];
    const float* T         = (const float*)d_in[3];
    const float* W_u       = (const float*)d_in[4];
    const float* W_p       = (const float*)d_in[5];
    const float* W_T_1     = (const float*)d_in[6];
    const float* W_T_2     = (const float*)d_in[7];
    const float* b_T       = (const float*)d_in[8];
    const float* W_p_      = (const float*)d_in[9];
    const int*   edge_index = (const int*)d_in[10];
    const int*   user_ptr   = (const int*)d_in[11];
    const int*   POI_ptr    = (const int*)d_in[12];

    const int E       = in_sizes[10] / 2;   // 4096
    const int N_users = in_sizes[0] / D;    // 10000
    const int N       = in_sizes[1] / D;    // 50000
    const int N_T2    = in_sizes[7];        // 2048
    const int N_T1    = in_sizes[6] / D;    // 2048

    float* ws_f  = (float*)d_ws;
    float* tmp   = ws_f;                    // N_T1
    float* pu_P  = ws_f + N_T1;             // D
    float* pu_U  = pu_P + D;                // D
    int*   flags = (int*)(pu_U + D);        // 2N ints, interleaved {tail, neigh}

    // 1) flag init (grid-stride) + tmp = T @ W_T_2
    k_pre<<<N_T1, 256, 0, stream>>>(T, W_T_2, tmp, flags, 2 * N, N_T2 / 4);

    // 2) t_vec rows (+ per-element dot products) + edge classifier block
    k_tvec2<<<D + 1, 256, 0, stream>>>(W_T_1, tmp, b_T, x, s_u, user_ptr,
                                       POI_ptr, edge_index, flags,
                                       pu_P, pu_U, N_T1 / 4, E);

    // 3) fused copy + all row updates, 8 rows per block
    const int total_rows = N_users + N;
    k_mega8<<<(total_rows + 7) / 8, 256, 0, stream>>>(
        s_u, x, edge_attr, W_u, W_p, W_p_, user_ptr, POI_ptr,
        flags, pu_P, pu_U, (float*)d_out, N_users, total_rows);
}

// Round 7
// 109.338 us; speedup vs baseline: 11.9034x; 11.9034x over previous
//
#include <hip/hip_runtime.h>
#include <math.h>
#include <limits.h>

#define D 1024  // state dim, fixed by the problem

typedef float f32x4 __attribute__((ext_vector_type(4)));

__device__ __forceinline__ float sigmoidf_(float v) {
    return 1.0f / (1.0f + expf(-v));
}

// Block-wide sum reduce for blockDim.x == 256 (4 waves). Broadcasts result.
// Trailing barrier makes repeated calls safe.
__device__ __forceinline__ float block_reduce_sum256(float v) {
    #pragma unroll
    for (int off = 32; off; off >>= 1) v += __shfl_down(v, off, 64);
    __shared__ float sm[4];
    int lane = threadIdx.x & 63, w = threadIdx.x >> 6;
    if (lane == 0) sm[w] = v;
    __syncthreads();
    float s = sm[0] + sm[1] + sm[2] + sm[3];
    __syncthreads();
    return s;
}

// Grid = N_T1 blocks. Every block: grid-stride init of the flag arrays to -1
// (2N ints, <=1 store per thread). Then tmp[row] = T[row,:] @ W_T_2.
__global__ void k_pre(const float* __restrict__ T,
                      const float* __restrict__ w,
                      float* __restrict__ tmp,
                      int* __restrict__ flags,   // tail_edge ++ neigh_edge
                      int n_flags, int t4 /* = N_T2/4 */) {
    const int tid = threadIdx.x;
    int gid = blockIdx.x * 256 + tid;
    int gsz = gridDim.x * 256;
    for (int i = gid; i < n_flags; i += gsz) flags[i] = -1;

    const int row = blockIdx.x;
    const float4* Tr = (const float4*)(T + (size_t)row * (size_t)(t4 * 4));
    const float4* wv = (const float4*)w;
    float acc = 0.f;
    for (int i = tid; i < t4; i += 256) {
        float4 a = Tr[i], c = wv[i];
        acc += a.x * c.x + a.y * c.y + a.z * c.z + a.w * c.w;
    }
    float s = block_reduce_sum256(acc);
    if (tid == 0) tmp[row] = s;
}

// Grid = D+1 blocks.
// Blocks [0,D): t = sigmoid(W_T_1[row,:] @ tmp + b_T[row]);
//   pu_P[row] = x[POI,row]*t ; pu_U[row] = s_u[user,row]*t.
// Block D: edge classification on the pre-initialized flags:
//   tail_edge[t]  = max e with heads[e]==POI              (np last-wins)
//   neigh_edge[h] = max e with e!=POI_index && tail_edge[tails[e]]>=0
__global__ void k_tvec2(const float* __restrict__ W_T_1,
                        const float* __restrict__ tmp,
                        const float* __restrict__ b_T,
                        const float* __restrict__ x,
                        const float* __restrict__ s_u,
                        const int* __restrict__ user_ptr,
                        const int* __restrict__ POI_ptr,
                        const int* __restrict__ edge_index,
                        int* __restrict__ tail_edge,
                        int* __restrict__ neigh_edge,
                        float* __restrict__ pu_P,
                        float* __restrict__ pu_U,
                        int k4 /* = N_T1/4 */, int E) {
    const int tid = threadIdx.x;
    if (blockIdx.x == gridDim.x - 1) {  // classifier block
        const int POI = POI_ptr[0];
        for (int e = tid; e < E; e += 256)
            if (edge_index[e] == POI)
                atomicMax(&tail_edge[edge_index[E + e]], e);
        __syncthreads();
        for (int e = tid; e < E; e += 256) {
            if (e == POI) continue;  // neigh_mask.at[POI_index].set(False)
            // read via atomic path (L2) so phase-1 results are visible
            int te = atomicMax(&tail_edge[edge_index[E + e]], INT_MIN);
            if (te >= 0) atomicMax(&neigh_edge[edge_index[e]], e);
        }
        return;
    }
    const int row = blockIdx.x;  // D rows
    const float4* Wr = (const float4*)(W_T_1 + (size_t)row * (size_t)(k4 * 4));
    const float4* tv = (const float4*)tmp;
    float acc = 0.f;
    for (int i = tid; i < k4; i += 256) {
        float4 a = Wr[i], c = tv[i];
        acc += a.x * c.x + a.y * c.y + a.z * c.z + a.w * c.w;
    }
    float s = block_reduce_sum256(acc);
    if (tid == 0) {
        float t = sigmoidf_(s + b_T[row]);
        pu_P[row] = x[(size_t)POI_ptr[0] * D + row] * t;
        pu_U[row] = s_u[(size_t)user_ptr[0] * D + row] * t;
    }
}

// Grid = ceil((N_users+N)/8) blocks x 256 threads; 8 rows per block, each
// thread owns one float4 slot of all 8 rows (speculative loads -> 8x MLP).
// Deterministic single writer per row:
//   s_u region: user row -> sigmoid(u + W_u*dotP); else stream copy.
//   x region:   neigh winner > tail winner > POI row > stream copy,
//   neigh base = post-tail-scatter value (matches reference order).
// All branches are block-uniform, so the barrier-based reductions are safe.
__global__ void k_mega8(const float* __restrict__ s_u,
                        const float* __restrict__ x,
                        const float* __restrict__ edge_attr,
                        const float* __restrict__ W_u,
                        const float* __restrict__ W_p,
                        const float* __restrict__ Wp_row,
                        const int* __restrict__ user_ptr,
                        const int* __restrict__ POI_ptr,
                        const int* __restrict__ tail_edge,
                        const int* __restrict__ neigh_edge,
                        const float* __restrict__ pu_P,
                        const float* __restrict__ pu_U,
                        float* __restrict__ out,
                        int N_users, int total_rows) {
    const int tid = threadIdx.x;
    const int base = blockIdx.x * 8;
    const int user = user_ptr[0], POI = POI_ptr[0];

    // speculative row loads (used by copy path, user path, and neigh-base)
    f32x4 v[8];
    #pragma unroll
    for (int k = 0; k < 8; k++) {
        int r = base + k;
        if (r >= total_rows) continue;
        const float* src = (r < N_users) ? s_u + (size_t)r * D
                                         : x + (size_t)(r - N_users) * D;
        v[k] = __builtin_nontemporal_load((const f32x4*)src + tid);
    }

    int te[8], ne[8];
    bool sp[8];
    #pragma unroll
    for (int k = 0; k < 8; k++) {
        int r = base + k;
        te[k] = -1; ne[k] = -1; sp[k] = false;
        if (r >= total_rows) continue;
        if (r < N_users) {
            sp[k] = (r == user);
        } else {
            int j = r - N_users;
            te[k] = tail_edge[j];
            ne[k] = neigh_edge[j];
            sp[k] = (te[k] >= 0) || (ne[k] >= 0) || (j == POI);
        }
    }

    #pragma unroll
    for (int k = 0; k < 8; k++) {
        int r = base + k;
        if (r >= total_rows) continue;
        f32x4* dst = (f32x4*)(out + (size_t)r * D) + tid;
        if (!sp[k]) {  // plain stream copy
            __builtin_nontemporal_store(v[k], dst);
            continue;
        }
        if (r < N_users) {  // user row
            f32x4 pp = ((const f32x4*)pu_P)[tid];
            float dotP = block_reduce_sum256(pp.x + pp.y + pp.z + pp.w);
            f32x4 wu = ((const f32x4*)W_u)[tid];
            f32x4 o;
            o.x = sigmoidf_(v[k].x + wu.x * dotP);
            o.y = sigmoidf_(v[k].y + wu.y * dotP);
            o.z = sigmoidf_(v[k].z + wu.z * dotP);
            o.w = sigmoidf_(v[k].w + wu.w * dotP);
            __builtin_nontemporal_store(o, dst);
            continue;
        }
        const int j = r - N_users;
        // new_POI element: sigmoid(x[POI] + W_p * dotU)
        f32x4 uu = ((const f32x4*)pu_U)[tid];
        float dotU = block_reduce_sum256(uu.x + uu.y + uu.z + uu.w);
        f32x4 xp = ((const f32x4*)(x + (size_t)POI * D))[tid];
        f32x4 wp = ((const f32x4*)W_p)[tid];
        f32x4 np;
        np.x = sigmoidf_(xp.x + wp.x * dotU);
        np.y = sigmoidf_(xp.y + wp.y * dotU);
        np.z = sigmoidf_(xp.z + wp.z * dotU);
        np.w = sigmoidf_(xp.w + wp.w * dotU);
        // base value: x state after POI-set and tail-scatter
        f32x4 hv;
        if (te[k] >= 0) {
            f32x4 b = ((const f32x4*)(edge_attr + (size_t)te[k] * D))[tid];
            hv = np + b;
        } else if (j == POI) {
            hv = np;
        } else {
            hv = v[k];
        }
        if (ne[k] < 0) {  // tail winner or untouched POI row
            __builtin_nontemporal_store(hv, dst);
            continue;
        }
        // neigh winner: sigmoid(hv + dot(hv - edge_attr[ne], W_p_))
        f32x4 ev = ((const f32x4*)(edge_attr + (size_t)ne[k] * D))[tid];
        f32x4 w = ((const f32x4*)Wp_row)[tid];
        f32x4 dd = hv - ev;
        float acc = dd.x * w.x + dd.y * w.y + dd.z * w.z + dd.w * w.w;
        float scal = block_reduce_sum256(acc);
        f32x4 o;
        o.x = sigmoidf_(hv.x + scal);
        o.y = sigmoidf_(hv.y + scal);
        o.z = sigmoidf_(hv.z + scal);
        o.w = sigmoidf_(hv.w + scal);
        __builtin_nontemporal_store(o, dst);
    }
}

extern "C" void kernel_launch(void* const* d_in, const int* in_sizes, int n_in,
                              void* d_out, int out_size, void* d_ws, size_t ws_size,
                              hipStream_t stream) {
    const float* s_u       = (const float*)d_in[0];
    const float* x         = (const float*)d_in[1];
    const float* edge_attr = (const float*)d_in[2];
    const float* T         = (const float*)d_in[3];
    const float* W_u       = (const float*)d_in[4];
    const float* W_p       = (const float*)d_in[5];
    const float* W_T_1     = (const float*)d_in[6];
    const float* W_T_2     = (const float*)d_in[7];
    const float* b_T       = (const float*)d_in[8];
    const float* W_p_      = (const float*)d_in[9];
    const int*   edge_index = (const int*)d_in[10];
    const int*   user_ptr   = (const int*)d_in[11];
    const int*   POI_ptr    = (const int*)d_in[12];

    const int E       = in_sizes[10] / 2;   // 4096
    const int N_users = in_sizes[0] / D;    // 10000
    const int N       = in_sizes[1] / D;    // 50000
    const int N_T2    = in_sizes[7];        // 2048
    const int N_T1    = in_sizes[6] / D;    // 2048

    float* ws_f       = (float*)d_ws;
    float* tmp        = ws_f;                       // N_T1
    float* pu_P       = ws_f + N_T1;                // D
    float* pu_U       = pu_P + D;                   // D
    int*   tail_edge  = (int*)(pu_U + D);           // N
    int*   neigh_edge = tail_edge + N;              // N (contiguous with tail)

    // 1) flag init (grid-stride) + tmp = T @ W_T_2
    k_pre<<<N_T1, 256, 0, stream>>>(T, W_T_2, tmp, tail_edge, 2 * N, N_T2 / 4);

    // 2) t_vec rows (+ per-element dot products) + edge classifier block
    k_tvec2<<<D + 1, 256, 0, stream>>>(W_T_1, tmp, b_T, x, s_u, user_ptr,
                                       POI_ptr, edge_index, tail_edge,
                                       neigh_edge, pu_P, pu_U, N_T1 / 4, E);

    // 3) fused copy + all row updates, 8 rows per block
    const int total_rows = N_users + N;
    k_mega8<<<(total_rows + 7) / 8, 256, 0, stream>>>(
        s_u, x, edge_attr, W_u, W_p, W_p_, user_ptr, POI_ptr,
        tail_edge, neigh_edge, pu_P, pu_U, (float*)d_out, N_users, total_rows);
}